// Round 9
// baseline (299.893 us; speedup 1.0000x reference)
//
#include <hip/hip_runtime.h>
#include <hip/hip_bf16.h>

typedef unsigned short u16;
typedef unsigned int   u32;

using bf16x8 = __attribute__((ext_vector_type(8))) short;
using f32x4  = __attribute__((ext_vector_type(4))) float;

// B=2, L=2048, IN_DIM=1024, H=16, KD=64, M=B*L=4096, SCALE=8
#define SEQ  2048
#define NZ   32
#define KTOT 1024
#define NTOT 1024
// 0.125 * log2(e): softmax in exp2 domain
#define SC2  0.18033688011112042f

__device__ __forceinline__ u16 f2bf(float f) {
    union { float f; u32 u; } x; x.f = f;
    u32 r = x.u + 0x7fffu + ((x.u >> 16) & 1u);
    return (u16)(r >> 16);
}

// async global->LDS, 16B per lane; lds base wave-uniform (HW adds lane*16)
__device__ __forceinline__ void gl_lds16(const u16* g, u16* ldsbase) {
    __builtin_amdgcn_global_load_lds(
        (const __attribute__((address_space(1))) u32*)g,
        (__attribute__((address_space(3))) u32*)ldsbase, 16, 0, 0);
}

// register-direct K fragment load (HW-verified in R2's passing run):
// dst[ks][fc] lane(g,li) = K[krow0 + fc*16 + li][ks*32 + g*8 + e]
__device__ __forceinline__ void ldk8(bf16x8 (&dst)[2][4], const u16* kbase,
                                     int krow0, int klo) {
#pragma unroll
    for (int ks = 0; ks < 2; ++ks)
#pragma unroll
        for (int fc = 0; fc < 4; ++fc)
            dst[ks][fc] = *(const bf16x8*)
                &kbase[(size_t)(krow0 + fc * 16) * 64 + ks * 32 + klo];
}

// pass-A half step (1 q-set): 8 MFMA on one 64-row K-tile + exp2 sums
__device__ __forceinline__ void passa_half1(const bf16x8 (&kr)[2][4],
                                            const bf16x8 (&aq)[2],
                                            float& s) {
    f32x4 sv[4];
#pragma unroll
    for (int fc = 0; fc < 4; ++fc) sv[fc] = (f32x4){0.f, 0.f, 0.f, 0.f};
    __builtin_amdgcn_s_setprio(1);
#pragma unroll
    for (int ks = 0; ks < 2; ++ks)
#pragma unroll
        for (int fc = 0; fc < 4; ++fc)
            sv[fc] = __builtin_amdgcn_mfma_f32_16x16x32_bf16(
                kr[ks][fc], aq[ks], sv[fc], 0, 0, 0);
    __builtin_amdgcn_s_setprio(0);
    float a = 0.f;
#pragma unroll
    for (int fc = 0; fc < 4; ++fc)
#pragma unroll
        for (int reg = 0; reg < 4; ++reg)
            a += __builtin_amdgcn_exp2f(sv[fc][reg] * SC2);
    s += a;
}

// =====================================================================
// prep: merged f32->bf16 cast of q,k,v into qb[3][4096][1024]  (blocks
// 0..6143) + weight transpose/cast WT[z][n][k]=bf16(W_z[k][n]) (blocks
// 6144..7167).
// =====================================================================
__global__ __launch_bounds__(256) void prep_k(const float* __restrict__ q,
                                              const float* __restrict__ k,
                                              const float* __restrict__ v,
                                              const float* __restrict__ W0,
                                              const float* __restrict__ W1,
                                              const float* __restrict__ W2,
                                              const float* __restrict__ W3,
                                              u16* __restrict__ qb,
                                              u16* __restrict__ WT) {
    __shared__ u16 t[64 * 65];
    const int tid = threadIdx.x;
    const int b = blockIdx.x;
    if (b < 6144) {
        const int zc = b >> 11;
        const int xc = b & 2047;
        const float* src = (zc == 0) ? q : (zc == 1) ? k : v;
        u16* dst = qb + (size_t)zc * 4096 * 1024;
        int off = xc * 2048 + tid * 8;
        float4 v0 = *(const float4*)&src[off];
        float4 v1 = *(const float4*)&src[off + 4];
        uint4 o;
        o.x = (u32)f2bf(v0.x) | ((u32)f2bf(v0.y) << 16);
        o.y = (u32)f2bf(v0.z) | ((u32)f2bf(v0.w) << 16);
        o.z = (u32)f2bf(v1.x) | ((u32)f2bf(v1.y) << 16);
        o.w = (u32)f2bf(v1.z) | ((u32)f2bf(v1.w) << 16);
        *(uint4*)&dst[off] = o;
        return;
    }
    const int tt = b - 6144;
    const int zz = tt >> 8;
    const int bx = tt & 15, by = (tt >> 4) & 15;
    const float* W = (zz == 0) ? W0 : (zz == 1) ? W1 : (zz == 2) ? W2 : W3;
    u16* out = WT + (size_t)zz * 1024 * 1024;
    const int n0 = bx * 64, k0 = by * 64;
#pragma unroll
    for (int it = 0; it < 4; ++it) {
        int flat = it * 256 + tid;
        int r = flat >> 4, c4 = (flat & 15) * 4;
        float4 vv = *(const float4*)&W[(k0 + r) * 1024 + n0 + c4];
        t[r * 65 + c4 + 0] = f2bf(vv.x);
        t[r * 65 + c4 + 1] = f2bf(vv.y);
        t[r * 65 + c4 + 2] = f2bf(vv.z);
        t[r * 65 + c4 + 3] = f2bf(vv.w);
    }
    __syncthreads();
#pragma unroll
    for (int it = 0; it < 2; ++it) {
        int flat = it * 256 + tid;
        int rn = flat >> 3, c8 = (flat & 7) * 8;
        u32 p[4];
#pragma unroll
        for (int e = 0; e < 4; ++e) {
            u32 lo = t[(c8 + 2 * e + 0) * 65 + rn];
            u32 hi = t[(c8 + 2 * e + 1) * 65 + rn];
            p[e] = lo | (hi << 16);
        }
        uint4 o; o.x = p[0]; o.y = p[1]; o.z = p[2]; o.w = p[3];
        *(uint4*)&out[(n0 + rn) * 1024 + k0 + c8] = o;
    }
}

// =====================================================================
// QKV projection GEMM (R1-proven): 128x128 tile, BK=32, 4 waves (2x2),
// grid (8, 32, 3). LDS-transpose epilogue.
// =====================================================================
__global__ __launch_bounds__(256) void qkvproj_k(const u16* __restrict__ qb,
                                                 const u16* __restrict__ wt,
                                                 const float* __restrict__ bq,
                                                 const float* __restrict__ bk,
                                                 const float* __restrict__ bv,
                                                 u16* __restrict__ qh,
                                                 u16* __restrict__ kh,
                                                 u16* __restrict__ vhT) {
    __shared__ u16 As[128 * 32];
    __shared__ u16 Bs[128 * 32];
    __shared__ u16 T[128 * 132];
    const int zz = blockIdx.z;
    const u16*   A    = qb + (size_t)zz * 4096 * 1024;
    const u16*   WT   = wt + (size_t)zz * 1024 * 1024;
    const float* bias = (zz == 0) ? bq : (zz == 1) ? bk : bv;
    const bool vmode = (zz == 2);

    const int tid = threadIdx.x;
    const int m0 = blockIdx.y * 128;
    const int n0 = blockIdx.x * 128;
    const int wid = tid >> 6, lane = tid & 63;
    const int wrow = wid >> 1, wcol = wid & 1;
    const int g = lane >> 4, li = lane & 15;

    f32x4 acc[4][4];
#pragma unroll
    for (int a = 0; a < 4; ++a)
#pragma unroll
        for (int b = 0; b < 4; ++b) acc[a][b] = (f32x4){0.f, 0.f, 0.f, 0.f};

    for (int kt = 0; kt < KTOT / 32; ++kt) {
        const int kb = kt * 32;
#pragma unroll
        for (int cc = 0; cc < 2; ++cc) {
            int c = wid + cc * 4;
            gl_lds16(&A[(m0 + c * 16 + (lane >> 2)) * KTOT + kb + (lane & 3) * 8],
                     &As[c * 512]);
            gl_lds16(&WT[(n0 + c * 16 + (lane >> 2)) * KTOT + kb + (lane & 3) * 8],
                     &Bs[c * 512]);
        }
        __syncthreads();
        bf16x8 af[4], bfr[4];
#pragma unroll
        for (int fr = 0; fr < 4; ++fr)
            af[fr] = *(const bf16x8*)&As[(wrow * 64 + fr * 16 + li) * 32 + g * 8];
#pragma unroll
        for (int fc = 0; fc < 4; ++fc)
            bfr[fc] = *(const bf16x8*)&Bs[(wcol * 64 + fc * 16 + li) * 32 + g * 8];
#pragma unroll
        for (int fr = 0; fr < 4; ++fr)
#pragma unroll
            for (int fc = 0; fc < 4; ++fc)
                acc[fr][fc] = __builtin_amdgcn_mfma_f32_16x16x32_bf16(
                    af[fr], bfr[fc], acc[fr][fc], 0, 0, 0);
        __syncthreads();
    }

#pragma unroll
    for (int fr = 0; fr < 4; ++fr)
#pragma unroll
        for (int fc = 0; fc < 4; ++fc)
#pragma unroll
            for (int reg = 0; reg < 4; ++reg) {
                int rl = wrow * 64 + fr * 16 + g * 4 + reg;
                int cl = wcol * 64 + fc * 16 + li;
                u16 bv16 = f2bf(acc[fr][fc][reg] + bias[n0 + cl]);
                if (!vmode) T[rl * 132 + cl] = bv16;
                else        T[cl * 132 + rl] = bv16;
            }
    __syncthreads();

    const int bb2 = m0 >> 11, ml = m0 & 2047;
    const int lc8 = (tid & 7) * 8;
#pragma unroll
    for (int it = 0; it < 8; ++it) {
        int idx = it * 32 + (tid >> 3);
        int row = idx >> 1, half = idx & 1;
        uint4 val = *(const uint4*)&T[row * 132 + half * 64 + lc8];
        if (!vmode) {
            int h = (n0 >> 6) + half;
            u16* dst = (blockIdx.z == 0) ? qh : kh;
            *(uint4*)&dst[(((h * 2 + bb2) * 2048 + ml + row) << 6) + lc8] = val;
        } else {
            int cg = n0 + row;
            int h = cg >> 6, d = cg & 63;
            *(uint4*)&vhT[(((h * 2 + bb2) * 64 + d) << 11) + ml + half * 64 + lc8] = val;
        }
    }
}

// =====================================================================
// Out-projection GEMM: y = attnout(bf16) @ WoT^T + bo + res (f32 out).
// R5 (kept): 64x128 tile, grid (8,64) = 512 blocks -> 2 blocks/CU.
// =====================================================================
__global__ __launch_bounds__(256) void outproj_k(const u16* __restrict__ A,
                                                 const u16* __restrict__ WT,
                                                 const float* __restrict__ bias,
                                                 const float* __restrict__ res,
                                                 float* __restrict__ outp) {
    __shared__ u16 As[64 * 32];
    __shared__ u16 Bs[128 * 32];
    const int tid = threadIdx.x;
    const int m0 = blockIdx.y * 64;
    const int n0 = blockIdx.x * 128;
    const int wid = tid >> 6, lane = tid & 63;
    const int wrow = wid >> 1, wcol = wid & 1;
    const int g = lane >> 4, li = lane & 15;

    f32x4 acc[2][4];
#pragma unroll
    for (int a = 0; a < 2; ++a)
#pragma unroll
        for (int b = 0; b < 4; ++b) acc[a][b] = (f32x4){0.f, 0.f, 0.f, 0.f};

    for (int kt = 0; kt < KTOT / 32; ++kt) {
        const int kb = kt * 32;
        gl_lds16(&A[(m0 + wid * 16 + (lane >> 2)) * KTOT + kb + (lane & 3) * 8],
                 &As[wid * 512]);
#pragma unroll
        for (int cc = 0; cc < 2; ++cc) {
            int c = wid * 2 + cc;
            gl_lds16(&WT[(n0 + c * 16 + (lane >> 2)) * KTOT + kb + (lane & 3) * 8],
                     &Bs[c * 512]);
        }
        __syncthreads();
        bf16x8 af[2], bfr[4];
#pragma unroll
        for (int fr = 0; fr < 2; ++fr)
            af[fr] = *(const bf16x8*)&As[(wrow * 32 + fr * 16 + li) * 32 + g * 8];
#pragma unroll
        for (int fc = 0; fc < 4; ++fc)
            bfr[fc] = *(const bf16x8*)&Bs[(wcol * 64 + fc * 16 + li) * 32 + g * 8];
#pragma unroll
        for (int fr = 0; fr < 2; ++fr)
#pragma unroll
            for (int fc = 0; fc < 4; ++fc)
                acc[fr][fc] = __builtin_amdgcn_mfma_f32_16x16x32_bf16(
                    af[fr], bfr[fc], acc[fr][fc], 0, 0, 0);
        __syncthreads();
    }

#pragma unroll
    for (int fr = 0; fr < 2; ++fr)
#pragma unroll
        for (int fc = 0; fc < 4; ++fc)
#pragma unroll
            for (int reg = 0; reg < 4; ++reg) {
                int r = m0 + wrow * 32 + fr * 16 + g * 4 + reg;
                int c = n0 + wcol * 64 + fc * 16 + li;
                outp[r * NTOT + c] = acc[fr][fc][reg] + bias[c] + res[r * NTOT + c];
            }
}

// =====================================================================
// Attention v13 = R7 (proven 244us: 4-wave/64-row blocks, 4 blocks/CU)
// with ONE change: pass A drops LDS staging entirely. Each wave reads
// its K fragments global->VGPR (ldk8, formula HW-verified in R2),
// register-double-buffered 64-row tiles -> ZERO barriers in pass A,
// zero LDS traffic outside pass B. No stores in flight during pass A
// (the R3 failure mode doesn't apply); 4 waves/block share addresses
// -> L1-hot. Pass B/grid/LDS(40KB)/occupancy: R7-exact.
// =====================================================================
__global__ __launch_bounds__(256, 4) void attn_k(const u16* __restrict__ qh,
                                                 const u16* __restrict__ kh,
                                                 const u16* __restrict__ vhT,
                                                 float* __restrict__ atn,
                                                 u16* __restrict__ attnout) {
    __shared__ u16 lds[20480];        // 40KB (pass B only)
    const int tid = threadIdx.x;
    const int D = blockIdx.x;
    const int z = D & 31, q0 = (D >> 5) * 64;
    const int h = z >> 1, bb = z & 1;
    const int wid = tid >> 6, lane = tid & 63, g = lane >> 4, li = lane & 15;
    const int row0 = wid * 16;
    const int zbase = z * SEQ;
    const int swz = li & 7;           // read-side row xor

    // Q fragments (B-operand): lane li -> q-row row0+li, k = ks*32+g*8+e
    bf16x8 aq[2];
#pragma unroll
    for (int ks = 0; ks < 2; ++ks)
        aq[ks] = *(const bf16x8*)
            &qh[(size_t)(zbase + q0 + row0 + li) * 64 + ks * 32 + g * 8];

    // ---------- pass A: row log-sums, register-direct K, no barriers ----
    float lmv;
    {
        float s = 0.f;
        const u16* kbase = kh + (size_t)zbase * 64;
        const int klo = li * 64 + g * 8;
        bf16x8 ka[2][4], kb[2][4];
        ldk8(ka, kbase, 0, klo);
        for (int t = 0; t < 32; t += 2) {
            ldk8(kb, kbase, (t + 1) * 64, klo);
            passa_half1(ka, aq, s);
            if (t < 30) ldk8(ka, kbase, (t + 2) * 64, klo);
            passa_half1(kb, aq, s);
        }
        s += __shfl_xor(s, 16, 64);
        s += __shfl_xor(s, 32, 64);
        lmv = __builtin_amdgcn_logf(s);          // log2(sum); p = exp2(S'-lmv)
    }

    // ---------------- pass B (R7-exact) ----------------
    u16* Ks = lds;                 // [2][4096]
    u16* Vs = lds + 8192;          // [2][4096]
    u16* Ps = lds + 16384;         // [4][1024]
    const int ar8 = lane >> 3;
    const int schunk = (lane & 7) ^ ar8;
    const u16* ksrc[2];
    const u16* vsrc[2];
#pragma unroll
    for (int cc = 0; cc < 2; ++cc) {
        int c = wid * 2 + cc;
        ksrc[cc] = &kh[(size_t)(zbase + c * 8 + ar8) * 64 + schunk * 8];
        vsrc[cc] = &vhT[(size_t)(z * 64 + c * 8 + ar8) * SEQ + schunk * 8];
        gl_lds16(ksrc[cc], &Ks[c * 512]);
        gl_lds16(vsrc[cc], &Vs[c * 512]);
    }
    __syncthreads();

    f32x4 oa[4];
#pragma unroll
    for (int fn = 0; fn < 4; ++fn) oa[fn] = (f32x4){0.f, 0.f, 0.f, 0.f};

    const u16* psw = &Ps[wid * 1024];     // this wave's 16x64 P slice
    const int prow = wid * 1024 + li * 64;
    for (int kt = 0; kt < 32; ++kt) {
        const int buf = kt & 1;
        const int k0 = kt * 64;
        if (kt < 31) {
#pragma unroll
            for (int cc = 0; cc < 2; ++cc) {
                int c = wid * 2 + cc;
                gl_lds16(ksrc[cc] + (size_t)(kt + 1) * 64 * 64,
                         &Ks[(buf ^ 1) * 4096 + c * 512]);
                gl_lds16(vsrc[cc] + (size_t)(kt + 1) * 64,
                         &Vs[(buf ^ 1) * 4096 + c * 512]);
            }
        }

        f32x4 sv[4];
#pragma unroll
        for (int fc = 0; fc < 4; ++fc) sv[fc] = (f32x4){0.f, 0.f, 0.f, 0.f};
        __builtin_amdgcn_s_setprio(1);
#pragma unroll
        for (int ks = 0; ks < 2; ++ks) {
#pragma unroll
            for (int fc = 0; fc < 4; ++fc) {
                bf16x8 kf = *(const bf16x8*)
                    &Ks[buf * 4096 + (fc * 16 + li) * 64 + (((ks * 4 + g) ^ swz) * 8)];
                sv[fc] = __builtin_amdgcn_mfma_f32_16x16x32_bf16(
                    kf, aq[ks], sv[fc], 0, 0, 0);
            }
        }
        __builtin_amdgcn_s_setprio(0);

        // p = exp2(S'-lm) -> bf16 pairs into Ps (swizzled chunks)
#pragma unroll
        for (int fc = 0; fc < 4; ++fc) {
            float p0 = __builtin_amdgcn_exp2f(sv[fc][0] * SC2 - lmv);
            float p1 = __builtin_amdgcn_exp2f(sv[fc][1] * SC2 - lmv);
            float p2 = __builtin_amdgcn_exp2f(sv[fc][2] * SC2 - lmv);
            float p3 = __builtin_amdgcn_exp2f(sv[fc][3] * SC2 - lmv);
            u32 w0 = (u32)f2bf(p0) | ((u32)f2bf(p1) << 16);
            u32 w1 = (u32)f2bf(p2) | ((u32)f2bf(p3) << 16);
            int pc = ((fc * 2 + (g >> 1)) ^ swz) * 8 + (g & 1) * 4;
            *(u32*)&Ps[prow + pc]     = w0;
            *(u32*)&Ps[prow + pc + 2] = w1;
        }

        // atn emit: transposed readback, 4 rows x 256B contiguous per instr
#pragma unroll
        for (int it2 = 0; it2 < 4; ++it2) {
            int row  = it2 * 4 + (lane >> 4);      // 0..15
            int col8 = lane & 15;                  // 8B unit (4 bf16) in row
            int lc   = col8 >> 1;                  // logical 16B chunk
            uint2 d2 = *(const uint2*)
                &psw[row * 64 + ((lc ^ (row & 7)) << 3) + ((col8 & 1) << 2)];
            f32x4 o4;
            union { u32 u; float f; } c0v, c1v, c2v, c3v;
            c0v.u = (d2.x & 0xffffu) << 16;  c1v.u = d2.x & 0xffff0000u;
            c2v.u = (d2.y & 0xffffu) << 16;  c3v.u = d2.y & 0xffff0000u;
            o4[0] = c0v.f; o4[1] = c1v.f; o4[2] = c2v.f; o4[3] = c3v.f;
            __builtin_nontemporal_store(o4, (f32x4*)
                &atn[(size_t)(zbase + q0 + row0 + row) * SEQ + k0 + col8 * 4]);
        }

        // PV: O^T = V^T * P^T  (A = V-frag, B = P-frag)
        __builtin_amdgcn_s_setprio(1);
#pragma unroll
        for (int ks = 0; ks < 2; ++ks) {
            bf16x8 pf = *(const bf16x8*)&Ps[prow + (((ks * 4 + g) ^ swz) * 8)];
#pragma unroll
            for (int fn = 0; fn < 4; ++fn) {
                bf16x8 vf = *(const bf16x8*)
                    &Vs[buf * 4096 + (fn * 16 + li) * 64 + (((ks * 4 + g) ^ swz) * 8)];
                oa[fn] = __builtin_amdgcn_mfma_f32_16x16x32_bf16(
                    vf, pf, oa[fn], 0, 0, 0);
            }
        }
        __builtin_amdgcn_s_setprio(0);
        // counted wait: queue = [<=4 prior stores][4 gl_lds][4 new stores];
        // vmcnt(4) drains the prefetch loads, lets this tile's stores fly.
        asm volatile("s_waitcnt vmcnt(4) lgkmcnt(0)" ::: "memory");
        __builtin_amdgcn_s_barrier();
    }

    // epilogue: O^T regs -> attnout[bb*2048 + r][h*64 + d], 8B packed stores
#pragma unroll
    for (int fn = 0; fn < 4; ++fn) {
        u32 w0 = (u32)f2bf(oa[fn][0]) | ((u32)f2bf(oa[fn][1]) << 16);
        u32 w1 = (u32)f2bf(oa[fn][2]) | ((u32)f2bf(oa[fn][3]) << 16);
        uint2 wv; wv.x = w0; wv.y = w1;
        *(uint2*)&attnout[(size_t)(bb * SEQ + q0 + row0 + li) * 1024
                          + h * 64 + fn * 16 + g * 4] = wv;
    }
}

// =====================================================================
// Row LayerNorm
// =====================================================================
__global__ __launch_bounds__(256) void ln_k(const float* __restrict__ y,
                                            const float* __restrict__ gamma,
                                            const float* __restrict__ beta,
                                            float* __restrict__ out) {
    __shared__ float red[8];
    const int row = blockIdx.x, tid = threadIdx.x;
    float4 v = *(const float4*)&y[row * 1024 + tid * 4];
    float s = v.x + v.y + v.z + v.w;
    float sq = v.x * v.x + v.y * v.y + v.z * v.z + v.w * v.w;
#pragma unroll
    for (int msk = 1; msk <= 32; msk <<= 1) {
        s += __shfl_xor(s, msk, 64);
        sq += __shfl_xor(sq, msk, 64);
    }
    const int wid = tid >> 6;
    if ((tid & 63) == 0) { red[wid * 2] = s; red[wid * 2 + 1] = sq; }
    __syncthreads();
    s = red[0] + red[2] + red[4] + red[6];
    sq = red[1] + red[3] + red[5] + red[7];
    float mu = s * (1.0f / 1024.0f);
    float var = sq * (1.0f / 1024.0f) - mu * mu;
    float rs = rsqrtf(var + 1e-5f);
    float4 g4 = *(const float4*)&gamma[tid * 4];
    float4 b4 = *(const float4*)&beta[tid * 4];
    float4 o;
    o.x = (v.x - mu) * rs * g4.x + b4.x;
    o.y = (v.y - mu) * rs * g4.y + b4.y;
    o.z = (v.z - mu) * rs * g4.z + b4.z;
    o.w = (v.w - mu) * rs * g4.w + b4.w;
    *(float4*)&out[row * 1024 + tid * 4] = o;
}

// =====================================================================
extern "C" void kernel_launch(void* const* d_in, const int* in_sizes, int n_in,
                              void* d_out, int out_size, void* d_ws, size_t ws_size,
                              hipStream_t stream) {
    const float* q     = (const float*)d_in[0];
    const float* k     = (const float*)d_in[1];
    const float* v     = (const float*)d_in[2];
    const float* Wq    = (const float*)d_in[3];
    const float* bq    = (const float*)d_in[4];
    const float* Wk    = (const float*)d_in[5];
    const float* bk    = (const float*)d_in[6];
    const float* Wv    = (const float*)d_in[7];
    const float* bv    = (const float*)d_in[8];
    const float* Wo    = (const float*)d_in[9];
    const float* bo    = (const float*)d_in[10];
    const float* gamma = (const float*)d_in[11];
    const float* beta  = (const float*)d_in[12];

    float* out = (float*)d_out;               // [2,2048,1024] f32
    float* atn = out + 4096 * 1024;           // [32,2048,2048] f32

    // ws (56 MB): wt 8MB | qb 24MB {aliased: attnout 8MB, y 16MB} |
    //             qh 8 | kh 8 | vhT 8
    u16* wt  = (u16*)d_ws;                    // 4x [1024][1024] bf16
    u16* qb  = wt + 4 * 1024 * 1024;          // 3x [4096][1024] bf16
    u16* attnout = qb;                        // alias: qb dead after qkvproj
    float* y = (float*)(qb + 4096 * 1024);    // alias: after attnout region
    u16* qh  = qb + 3 * 4096 * 1024;
    u16* kh  = qh + NZ * SEQ * 64;
    u16* vhT = kh + NZ * SEQ * 64;
    u16* wto = wt + 3 * 1024 * 1024;

    dim3 tb(256);
    prep_k<<<dim3(7168), tb, 0, stream>>>(q, k, v, Wq, Wk, Wv, Wo, qb, wt);

    qkvproj_k<<<dim3(8, 32, 3), tb, 0, stream>>>(qb, wt, bq, bk, bv,
                                                 qh, kh, vhT);

    attn_k<<<dim3(1024), dim3(256), 0, stream>>>(qh, kh, vhT, atn, attnout);

    outproj_k<<<dim3(8, 64), tb, 0, stream>>>(attnout, wto, bo, q, y);

    ln_k<<<dim3(4096), tb, 0, stream>>>(y, gamma, beta, out);
}

// Round 10
// 242.288 us; speedup vs baseline: 1.2378x; 1.2378x over previous
//
#include <hip/hip_runtime.h>
#include <hip/hip_bf16.h>

typedef unsigned short u16;
typedef unsigned int   u32;

using bf16x8 = __attribute__((ext_vector_type(8))) short;
using f32x4  = __attribute__((ext_vector_type(4))) float;

// B=2, L=2048, IN_DIM=1024, H=16, KD=64, M=B*L=4096, SCALE=8
#define SEQ  2048
#define NZ   32
#define KTOT 1024
#define NTOT 1024
// 0.125 * log2(e): softmax in exp2 domain
#define SC2  0.18033688011112042f

__device__ __forceinline__ u16 f2bf(float f) {
    union { float f; u32 u; } x; x.f = f;
    u32 r = x.u + 0x7fffu + ((x.u >> 16) & 1u);
    return (u16)(r >> 16);
}

// async global->LDS, 16B per lane; lds base wave-uniform (HW adds lane*16)
__device__ __forceinline__ void gl_lds16(const u16* g, u16* ldsbase) {
    __builtin_amdgcn_global_load_lds(
        (const __attribute__((address_space(1))) u32*)g,
        (__attribute__((address_space(3))) u32*)ldsbase, 16, 0, 0);
}

// =====================================================================
// prep: merged f32->bf16 cast of q,k,v into qb[3][4096][1024]  (blocks
// 0..6143) + weight transpose/cast WT[z][n][k]=bf16(W_z[k][n]) (blocks
// 6144..7167).
// =====================================================================
__global__ __launch_bounds__(256) void prep_k(const float* __restrict__ q,
                                              const float* __restrict__ k,
                                              const float* __restrict__ v,
                                              const float* __restrict__ W0,
                                              const float* __restrict__ W1,
                                              const float* __restrict__ W2,
                                              const float* __restrict__ W3,
                                              u16* __restrict__ qb,
                                              u16* __restrict__ WT) {
    __shared__ u16 t[64 * 65];
    const int tid = threadIdx.x;
    const int b = blockIdx.x;
    if (b < 6144) {
        const int zc = b >> 11;
        const int xc = b & 2047;
        const float* src = (zc == 0) ? q : (zc == 1) ? k : v;
        u16* dst = qb + (size_t)zc * 4096 * 1024;
        int off = xc * 2048 + tid * 8;
        float4 v0 = *(const float4*)&src[off];
        float4 v1 = *(const float4*)&src[off + 4];
        uint4 o;
        o.x = (u32)f2bf(v0.x) | ((u32)f2bf(v0.y) << 16);
        o.y = (u32)f2bf(v0.z) | ((u32)f2bf(v0.w) << 16);
        o.z = (u32)f2bf(v1.x) | ((u32)f2bf(v1.y) << 16);
        o.w = (u32)f2bf(v1.z) | ((u32)f2bf(v1.w) << 16);
        *(uint4*)&dst[off] = o;
        return;
    }
    const int tt = b - 6144;
    const int zz = tt >> 8;
    const int bx = tt & 15, by = (tt >> 4) & 15;
    const float* W = (zz == 0) ? W0 : (zz == 1) ? W1 : (zz == 2) ? W2 : W3;
    u16* out = WT + (size_t)zz * 1024 * 1024;
    const int n0 = bx * 64, k0 = by * 64;
#pragma unroll
    for (int it = 0; it < 4; ++it) {
        int flat = it * 256 + tid;
        int r = flat >> 4, c4 = (flat & 15) * 4;
        float4 vv = *(const float4*)&W[(k0 + r) * 1024 + n0 + c4];
        t[r * 65 + c4 + 0] = f2bf(vv.x);
        t[r * 65 + c4 + 1] = f2bf(vv.y);
        t[r * 65 + c4 + 2] = f2bf(vv.z);
        t[r * 65 + c4 + 3] = f2bf(vv.w);
    }
    __syncthreads();
#pragma unroll
    for (int it = 0; it < 2; ++it) {
        int flat = it * 256 + tid;
        int rn = flat >> 3, c8 = (flat & 7) * 8;
        u32 p[4];
#pragma unroll
        for (int e = 0; e < 4; ++e) {
            u32 lo = t[(c8 + 2 * e + 0) * 65 + rn];
            u32 hi = t[(c8 + 2 * e + 1) * 65 + rn];
            p[e] = lo | (hi << 16);
        }
        uint4 o; o.x = p[0]; o.y = p[1]; o.z = p[2]; o.w = p[3];
        *(uint4*)&out[(n0 + rn) * 1024 + k0 + c8] = o;
    }
}

// =====================================================================
// QKV projection GEMM (R1-proven): 128x128 tile, BK=32, 4 waves (2x2).
// CHANGE (R10): chunked XCD swizzle (T1). Dispatch round-robins block
// ids across the 8 XCDs; remapping work = (flat%8)*96 + flat/8 gives
// each XCD a contiguous 96-block chunk -> per-XCD L2 footprint drops
// from ~full A (8MB) to ~3MB (L2-resident). Bijective: 768 % 8 == 0.
// =====================================================================
__global__ __launch_bounds__(256) void qkvproj_k(const u16* __restrict__ qb,
                                                 const u16* __restrict__ wt,
                                                 const float* __restrict__ bq,
                                                 const float* __restrict__ bk,
                                                 const float* __restrict__ bv,
                                                 u16* __restrict__ qh,
                                                 u16* __restrict__ kh,
                                                 u16* __restrict__ vhT) {
    __shared__ u16 As[128 * 32];
    __shared__ u16 Bs[128 * 32];
    __shared__ u16 T[128 * 132];
    // chunked XCD swizzle: work id from dispatch id
    const int flat = (blockIdx.z * 32 + blockIdx.y) * 8 + blockIdx.x;
    const int nf   = (flat & 7) * 96 + (flat >> 3);
    const int zz   = nf >> 8;
    const int rem  = nf & 255;
    const int m0   = (rem >> 3) * 128;
    const int n0   = (rem & 7) * 128;

    const u16*   A    = qb + (size_t)zz * 4096 * 1024;
    const u16*   WT   = wt + (size_t)zz * 1024 * 1024;
    const float* bias = (zz == 0) ? bq : (zz == 1) ? bk : bv;
    const bool vmode = (zz == 2);

    const int tid = threadIdx.x;
    const int wid = tid >> 6, lane = tid & 63;
    const int wrow = wid >> 1, wcol = wid & 1;
    const int g = lane >> 4, li = lane & 15;

    f32x4 acc[4][4];
#pragma unroll
    for (int a = 0; a < 4; ++a)
#pragma unroll
        for (int b = 0; b < 4; ++b) acc[a][b] = (f32x4){0.f, 0.f, 0.f, 0.f};

    for (int kt = 0; kt < KTOT / 32; ++kt) {
        const int kb = kt * 32;
#pragma unroll
        for (int cc = 0; cc < 2; ++cc) {
            int c = wid + cc * 4;
            gl_lds16(&A[(m0 + c * 16 + (lane >> 2)) * KTOT + kb + (lane & 3) * 8],
                     &As[c * 512]);
            gl_lds16(&WT[(n0 + c * 16 + (lane >> 2)) * KTOT + kb + (lane & 3) * 8],
                     &Bs[c * 512]);
        }
        __syncthreads();
        bf16x8 af[4], bfr[4];
#pragma unroll
        for (int fr = 0; fr < 4; ++fr)
            af[fr] = *(const bf16x8*)&As[(wrow * 64 + fr * 16 + li) * 32 + g * 8];
#pragma unroll
        for (int fc = 0; fc < 4; ++fc)
            bfr[fc] = *(const bf16x8*)&Bs[(wcol * 64 + fc * 16 + li) * 32 + g * 8];
#pragma unroll
        for (int fr = 0; fr < 4; ++fr)
#pragma unroll
            for (int fc = 0; fc < 4; ++fc)
                acc[fr][fc] = __builtin_amdgcn_mfma_f32_16x16x32_bf16(
                    af[fr], bfr[fc], acc[fr][fc], 0, 0, 0);
        __syncthreads();
    }

#pragma unroll
    for (int fr = 0; fr < 4; ++fr)
#pragma unroll
        for (int fc = 0; fc < 4; ++fc)
#pragma unroll
            for (int reg = 0; reg < 4; ++reg) {
                int rl = wrow * 64 + fr * 16 + g * 4 + reg;
                int cl = wcol * 64 + fc * 16 + li;
                u16 bv16 = f2bf(acc[fr][fc][reg] + bias[n0 + cl]);
                if (!vmode) T[rl * 132 + cl] = bv16;
                else        T[cl * 132 + rl] = bv16;
            }
    __syncthreads();

    const int bb2 = m0 >> 11, ml = m0 & 2047;
    const int lc8 = (tid & 7) * 8;
#pragma unroll
    for (int it = 0; it < 8; ++it) {
        int idx = it * 32 + (tid >> 3);
        int row = idx >> 1, half = idx & 1;
        uint4 val = *(const uint4*)&T[row * 132 + half * 64 + lc8];
        if (!vmode) {
            int h = (n0 >> 6) + half;
            u16* dst = (zz == 0) ? qh : kh;
            *(uint4*)&dst[(((h * 2 + bb2) * 2048 + ml + row) << 6) + lc8] = val;
        } else {
            int cg = n0 + row;
            int h = cg >> 6, d = cg & 63;
            *(uint4*)&vhT[(((h * 2 + bb2) * 64 + d) << 11) + ml + half * 64 + lc8] = val;
        }
    }
}

// =====================================================================
// Out-projection GEMM: y = attnout(bf16) @ WoT^T + bo + res (f32 out).
// R5 geometry (64x128, 512 blocks, 2 blocks/CU) + R10 chunked XCD
// swizzle: nf = (flat%8)*64 + flat/8 (bijective: 512 % 8 == 0).
// =====================================================================
__global__ __launch_bounds__(256) void outproj_k(const u16* __restrict__ A,
                                                 const u16* __restrict__ WT,
                                                 const float* __restrict__ bias,
                                                 const float* __restrict__ res,
                                                 float* __restrict__ outp) {
    __shared__ u16 As[64 * 32];
    __shared__ u16 Bs[128 * 32];
    const int flat = blockIdx.y * 8 + blockIdx.x;
    const int nf   = (flat & 7) * 64 + (flat >> 3);
    const int m0   = (nf >> 3) * 64;
    const int n0   = (nf & 7) * 128;
    const int tid = threadIdx.x;
    const int wid = tid >> 6, lane = tid & 63;
    const int wrow = wid >> 1, wcol = wid & 1;
    const int g = lane >> 4, li = lane & 15;

    f32x4 acc[2][4];
#pragma unroll
    for (int a = 0; a < 2; ++a)
#pragma unroll
        for (int b = 0; b < 4; ++b) acc[a][b] = (f32x4){0.f, 0.f, 0.f, 0.f};

    for (int kt = 0; kt < KTOT / 32; ++kt) {
        const int kb = kt * 32;
        gl_lds16(&A[(m0 + wid * 16 + (lane >> 2)) * KTOT + kb + (lane & 3) * 8],
                 &As[wid * 512]);
#pragma unroll
        for (int cc = 0; cc < 2; ++cc) {
            int c = wid * 2 + cc;
            gl_lds16(&WT[(n0 + c * 16 + (lane >> 2)) * KTOT + kb + (lane & 3) * 8],
                     &Bs[c * 512]);
        }
        __syncthreads();
        bf16x8 af[2], bfr[4];
#pragma unroll
        for (int fr = 0; fr < 2; ++fr)
            af[fr] = *(const bf16x8*)&As[(wrow * 32 + fr * 16 + li) * 32 + g * 8];
#pragma unroll
        for (int fc = 0; fc < 4; ++fc)
            bfr[fc] = *(const bf16x8*)&Bs[(wcol * 64 + fc * 16 + li) * 32 + g * 8];
#pragma unroll
        for (int fr = 0; fr < 2; ++fr)
#pragma unroll
            for (int fc = 0; fc < 4; ++fc)
                acc[fr][fc] = __builtin_amdgcn_mfma_f32_16x16x32_bf16(
                    af[fr], bfr[fc], acc[fr][fc], 0, 0, 0);
        __syncthreads();
    }

#pragma unroll
    for (int fr = 0; fr < 2; ++fr)
#pragma unroll
        for (int fc = 0; fc < 4; ++fc)
#pragma unroll
            for (int reg = 0; reg < 4; ++reg) {
                int r = m0 + wrow * 32 + fr * 16 + g * 4 + reg;
                int c = n0 + wcol * 64 + fc * 16 + li;
                outp[r * NTOT + c] = acc[fr][fc][reg] + bias[c] + res[r * NTOT + c];
            }
}

// =====================================================================
// Attention v11 (R7-proven, 244us): 4-wave/64-row blocks, LDS 40KB,
// grid 1024 => 4 blocks/CU (4 independent barrier groups). Pass A:
// no-max log-sum, 128-row K-tiles, gl_lds dbuf. Pass B: K/V LDS-staged,
// Ps transpose-emit, vmcnt(4) counted barrier wait. Reg-direct operand
// loads falsified 3x (R2/R3/R9): fragment loads scatter 16 cache lines
// per instr vs gl_lds's coalesced pattern — do not revisit.
// =====================================================================
__global__ __launch_bounds__(256, 4) void attn_k(const u16* __restrict__ qh,
                                                 const u16* __restrict__ kh,
                                                 const u16* __restrict__ vhT,
                                                 float* __restrict__ atn,
                                                 u16* __restrict__ attnout) {
    __shared__ u16 lds[20480];        // 40KB union
    const int tid = threadIdx.x;
    const int D = blockIdx.x;
    const int z = D & 31, q0 = (D >> 5) * 64;
    const int h = z >> 1, bb = z & 1;
    const int wid = tid >> 6, lane = tid & 63, g = lane >> 4, li = lane & 15;
    const int row0 = wid * 16;
    const int zbase = z * SEQ;
    const int swz = li & 7;           // read-side row xor

    // Q fragments (B-operand): lane li -> q-row row0+li, k = ks*32+g*8+e
    bf16x8 aq[2];
#pragma unroll
    for (int ks = 0; ks < 2; ++ks)
        aq[ks] = *(const bf16x8*)
            &qh[(size_t)(zbase + q0 + row0 + li) * 64 + ks * 32 + g * 8];

    // ---------------- pass A: row sums (no max), 128-row K-tiles ---------
    float lmv;
    {
        u16* KsA = lds;                          // [2][8192] u16 (32KB)
        const int ar = lane >> 3;
        const int ac = (lane & 7) ^ ar;          // pre-swizzled source chunk
        const u16* kA[4];
#pragma unroll
        for (int cc = 0; cc < 4; ++cc) {
            int c = wid * 4 + cc;
            kA[cc] = &kh[(size_t)(zbase + c * 8 + ar) * 64 + ac * 8];
            gl_lds16(kA[cc], &KsA[c * 512]);
        }
        __syncthreads();

        float s = 0.f;
        for (int kt = 0; kt < 16; ++kt) {
            const int buf = kt & 1;
            if (kt < 15) {
                const size_t nxt = (size_t)(kt + 1) * 128 * 64;
#pragma unroll
                for (int cc = 0; cc < 4; ++cc)
                    gl_lds16(kA[cc] + nxt,
                             &KsA[(buf ^ 1) * 8192 + (wid * 4 + cc) * 512]);
            }
            f32x4 sv[8];
#pragma unroll
            for (int fc = 0; fc < 8; ++fc) sv[fc] = (f32x4){0.f, 0.f, 0.f, 0.f};
            __builtin_amdgcn_s_setprio(1);
#pragma unroll
            for (int ks = 0; ks < 2; ++ks) {
#pragma unroll
                for (int fc = 0; fc < 8; ++fc) {
                    bf16x8 kf = *(const bf16x8*)
                        &KsA[buf * 8192 + (fc * 16 + li) * 64 + (((ks * 4 + g) ^ swz) * 8)];
                    sv[fc] = __builtin_amdgcn_mfma_f32_16x16x32_bf16(
                        kf, aq[ks], sv[fc], 0, 0, 0);
                }
            }
            __builtin_amdgcn_s_setprio(0);
            float ssum = 0.f;
#pragma unroll
            for (int fc = 0; fc < 8; ++fc)
#pragma unroll
                for (int reg = 0; reg < 4; ++reg)
                    ssum += __builtin_amdgcn_exp2f(sv[fc][reg] * SC2);
            s += ssum;
            __syncthreads();
        }
        s += __shfl_xor(s, 16, 64);
        s += __shfl_xor(s, 32, 64);
        lmv = __builtin_amdgcn_logf(s);          // log2(sum); p = exp2(S'-lmv)
    }

    // ---------------- pass B ----------------
    u16* Ks = lds;                 // [2][4096]
    u16* Vs = lds + 8192;          // [2][4096]
    u16* Ps = lds + 16384;         // [4][1024]
    const int ar8 = lane >> 3;
    const int schunk = (lane & 7) ^ ar8;
    const u16* ksrc[2];
    const u16* vsrc[2];
#pragma unroll
    for (int cc = 0; cc < 2; ++cc) {
        int c = wid * 2 + cc;
        ksrc[cc] = &kh[(size_t)(zbase + c * 8 + ar8) * 64 + schunk * 8];
        vsrc[cc] = &vhT[(size_t)(z * 64 + c * 8 + ar8) * SEQ + schunk * 8];
        gl_lds16(ksrc[cc], &Ks[c * 512]);
        gl_lds16(vsrc[cc], &Vs[c * 512]);
    }
    __syncthreads();

    f32x4 oa[4];
#pragma unroll
    for (int fn = 0; fn < 4; ++fn) oa[fn] = (f32x4){0.f, 0.f, 0.f, 0.f};

    const u16* psw = &Ps[wid * 1024];     // this wave's 16x64 P slice
    const int prow = wid * 1024 + li * 64;
    for (int kt = 0; kt < 32; ++kt) {
        const int buf = kt & 1;
        const int k0 = kt * 64;
        if (kt < 31) {
#pragma unroll
            for (int cc = 0; cc < 2; ++cc) {
                int c = wid * 2 + cc;
                gl_lds16(ksrc[cc] + (size_t)(kt + 1) * 64 * 64,
                         &Ks[(buf ^ 1) * 4096 + c * 512]);
                gl_lds16(vsrc[cc] + (size_t)(kt + 1) * 64,
                         &Vs[(buf ^ 1) * 4096 + c * 512]);
            }
        }

        f32x4 sv[4];
#pragma unroll
        for (int fc = 0; fc < 4; ++fc) sv[fc] = (f32x4){0.f, 0.f, 0.f, 0.f};
        __builtin_amdgcn_s_setprio(1);
#pragma unroll
        for (int ks = 0; ks < 2; ++ks) {
#pragma unroll
            for (int fc = 0; fc < 4; ++fc) {
                bf16x8 kf = *(const bf16x8*)
                    &Ks[buf * 4096 + (fc * 16 + li) * 64 + (((ks * 4 + g) ^ swz) * 8)];
                sv[fc] = __builtin_amdgcn_mfma_f32_16x16x32_bf16(
                    kf, aq[ks], sv[fc], 0, 0, 0);
            }
        }
        __builtin_amdgcn_s_setprio(0);

        // p = exp2(S'-lm) -> bf16 pairs into Ps (swizzled chunks)
#pragma unroll
        for (int fc = 0; fc < 4; ++fc) {
            float p0 = __builtin_amdgcn_exp2f(sv[fc][0] * SC2 - lmv);
            float p1 = __builtin_amdgcn_exp2f(sv[fc][1] * SC2 - lmv);
            float p2 = __builtin_amdgcn_exp2f(sv[fc][2] * SC2 - lmv);
            float p3 = __builtin_amdgcn_exp2f(sv[fc][3] * SC2 - lmv);
            u32 w0 = (u32)f2bf(p0) | ((u32)f2bf(p1) << 16);
            u32 w1 = (u32)f2bf(p2) | ((u32)f2bf(p3) << 16);
            int pc = ((fc * 2 + (g >> 1)) ^ swz) * 8 + (g & 1) * 4;
            *(u32*)&Ps[prow + pc]     = w0;
            *(u32*)&Ps[prow + pc + 2] = w1;
        }

        // atn emit: transposed readback, 4 rows x 256B contiguous per instr
#pragma unroll
        for (int it2 = 0; it2 < 4; ++it2) {
            int row  = it2 * 4 + (lane >> 4);      // 0..15
            int col8 = lane & 15;                  // 8B unit (4 bf16) in row
            int lc   = col8 >> 1;                  // logical 16B chunk
            uint2 d2 = *(const uint2*)
                &psw[row * 64 + ((lc ^ (row & 7)) << 3) + ((col8 & 1) << 2)];
            f32x4 o4;
            union { u32 u; float f; } c0v, c1v, c2v, c3v;
            c0v.u = (d2.x & 0xffffu) << 16;  c1v.u = d2.x & 0xffff0000u;
            c2v.u = (d2.y & 0xffffu) << 16;  c3v.u = d2.y & 0xffff0000u;
            o4[0] = c0v.f; o4[1] = c1v.f; o4[2] = c2v.f; o4[3] = c3v.f;
            __builtin_nontemporal_store(o4, (f32x4*)
                &atn[(size_t)(zbase + q0 + row0 + row) * SEQ + k0 + col8 * 4]);
        }

        // PV: O^T = V^T * P^T  (A = V-frag, B = P-frag)
        __builtin_amdgcn_s_setprio(1);
#pragma unroll
        for (int ks = 0; ks < 2; ++ks) {
            bf16x8 pf = *(const bf16x8*)&Ps[prow + (((ks * 4 + g) ^ swz) * 8)];
#pragma unroll
            for (int fn = 0; fn < 4; ++fn) {
                bf16x8 vf = *(const bf16x8*)
                    &Vs[buf * 4096 + (fn * 16 + li) * 64 + (((ks * 4 + g) ^ swz) * 8)];
                oa[fn] = __builtin_amdgcn_mfma_f32_16x16x32_bf16(
                    vf, pf, oa[fn], 0, 0, 0);
            }
        }
        __builtin_amdgcn_s_setprio(0);
        // counted wait: queue = [<=4 prior stores][4 gl_lds][4 new stores];
        // vmcnt(4) drains the prefetch loads, lets this tile's stores fly.
        asm volatile("s_waitcnt vmcnt(4) lgkmcnt(0)" ::: "memory");
        __builtin_amdgcn_s_barrier();
    }

    // epilogue: O^T regs -> attnout[bb*2048 + r][h*64 + d], 8B packed stores
#pragma unroll
    for (int fn = 0; fn < 4; ++fn) {
        u32 w0 = (u32)f2bf(oa[fn][0]) | ((u32)f2bf(oa[fn][1]) << 16);
        u32 w1 = (u32)f2bf(oa[fn][2]) | ((u32)f2bf(oa[fn][3]) << 16);
        uint2 wv; wv.x = w0; wv.y = w1;
        *(uint2*)&attnout[(size_t)(bb * SEQ + q0 + row0 + li) * 1024
                          + h * 64 + fn * 16 + g * 4] = wv;
    }
}

// =====================================================================
// Row LayerNorm
// =====================================================================
__global__ __launch_bounds__(256) void ln_k(const float* __restrict__ y,
                                            const float* __restrict__ gamma,
                                            const float* __restrict__ beta,
                                            float* __restrict__ out) {
    __shared__ float red[8];
    const int row = blockIdx.x, tid = threadIdx.x;
    float4 v = *(const float4*)&y[row * 1024 + tid * 4];
    float s = v.x + v.y + v.z + v.w;
    float sq = v.x * v.x + v.y * v.y + v.z * v.z + v.w * v.w;
#pragma unroll
    for (int msk = 1; msk <= 32; msk <<= 1) {
        s += __shfl_xor(s, msk, 64);
        sq += __shfl_xor(sq, msk, 64);
    }
    const int wid = tid >> 6;
    if ((tid & 63) == 0) { red[wid * 2] = s; red[wid * 2 + 1] = sq; }
    __syncthreads();
    s = red[0] + red[2] + red[4] + red[6];
    sq = red[1] + red[3] + red[5] + red[7];
    float mu = s * (1.0f / 1024.0f);
    float var = sq * (1.0f / 1024.0f) - mu * mu;
    float rs = rsqrtf(var + 1e-5f);
    float4 g4 = *(const float4*)&gamma[tid * 4];
    float4 b4 = *(const float4*)&beta[tid * 4];
    float4 o;
    o.x = (v.x - mu) * rs * g4.x + b4.x;
    o.y = (v.y - mu) * rs * g4.y + b4.y;
    o.z = (v.z - mu) * rs * g4.z + b4.z;
    o.w = (v.w - mu) * rs * g4.w + b4.w;
    *(float4*)&out[row * 1024 + tid * 4] = o;
}

// =====================================================================
extern "C" void kernel_launch(void* const* d_in, const int* in_sizes, int n_in,
                              void* d_out, int out_size, void* d_ws, size_t ws_size,
                              hipStream_t stream) {
    const float* q     = (const float*)d_in[0];
    const float* k     = (const float*)d_in[1];
    const float* v     = (const float*)d_in[2];
    const float* Wq    = (const float*)d_in[3];
    const float* bq    = (const float*)d_in[4];
    const float* Wk    = (const float*)d_in[5];
    const float* bk    = (const float*)d_in[6];
    const float* Wv    = (const float*)d_in[7];
    const float* bv    = (const float*)d_in[8];
    const float* Wo    = (const float*)d_in[9];
    const float* bo    = (const float*)d_in[10];
    const float* gamma = (const float*)d_in[11];
    const float* beta  = (const float*)d_in[12];

    float* out = (float*)d_out;               // [2,2048,1024] f32
    float* atn = out + 4096 * 1024;           // [32,2048,2048] f32

    // ws (56 MB): wt 8MB | qb 24MB {aliased: attnout 8MB, y 16MB} |
    //             qh 8 | kh 8 | vhT 8
    u16* wt  = (u16*)d_ws;                    // 4x [1024][1024] bf16
    u16* qb  = wt + 4 * 1024 * 1024;          // 3x [4096][1024] bf16
    u16* attnout = qb;                        // alias: qb dead after qkvproj
    float* y = (float*)(qb + 4096 * 1024);    // alias: after attnout region
    u16* qh  = qb + 3 * 4096 * 1024;
    u16* kh  = qh + NZ * SEQ * 64;
    u16* vhT = kh + NZ * SEQ * 64;
    u16* wto = wt + 3 * 1024 * 1024;

    dim3 tb(256);
    prep_k<<<dim3(7168), tb, 0, stream>>>(q, k, v, Wq, Wk, Wv, Wo, qb, wt);

    qkvproj_k<<<dim3(8, 32, 3), tb, 0, stream>>>(qb, wt, bq, bk, bv,
                                                 qh, kh, vhT);

    attn_k<<<dim3(1024), tb, 0, stream>>>(qh, kh, vhT, atn, attnout);

    outproj_k<<<dim3(8, 64), tb, 0, stream>>>(attnout, wto, bo, q, y);

    ln_k<<<dim3(4096), tb, 0, stream>>>(y, gamma, beta, out);
}

// Round 11
// 241.119 us; speedup vs baseline: 1.2438x; 1.0048x over previous
//
#include <hip/hip_runtime.h>
#include <hip/hip_bf16.h>

typedef unsigned short u16;
typedef unsigned int   u32;

using bf16x8 = __attribute__((ext_vector_type(8))) short;
using f32x4  = __attribute__((ext_vector_type(4))) float;

// B=2, L=2048, IN_DIM=1024, H=16, KD=64, M=B*L=4096, SCALE=8
#define SEQ  2048
#define NZ   32
#define KTOT 1024
#define NTOT 1024
// 0.125 * log2(e): softmax in exp2 domain
#define SC2  0.18033688011112042f

__device__ __forceinline__ u16 f2bf(float f) {
    union { float f; u32 u; } x; x.f = f;
    u32 r = x.u + 0x7fffu + ((x.u >> 16) & 1u);
    return (u16)(r >> 16);
}

// async global->LDS, 16B per lane; lds base wave-uniform (HW adds lane*16)
__device__ __forceinline__ void gl_lds16(const u16* g, u16* ldsbase) {
    __builtin_amdgcn_global_load_lds(
        (const __attribute__((address_space(1))) u32*)g,
        (__attribute__((address_space(3))) u32*)ldsbase, 16, 0, 0);
}

// =====================================================================
// prep: merged f32->bf16 cast of q,k,v into qb[3][4096][1024]  (blocks
// 0..6143) + weight transpose/cast WT[z][n][k]=bf16(W_z[k][n]) (blocks
// 6144..7167).
// =====================================================================
__global__ __launch_bounds__(256) void prep_k(const float* __restrict__ q,
                                              const float* __restrict__ k,
                                              const float* __restrict__ v,
                                              const float* __restrict__ W0,
                                              const float* __restrict__ W1,
                                              const float* __restrict__ W2,
                                              const float* __restrict__ W3,
                                              u16* __restrict__ qb,
                                              u16* __restrict__ WT) {
    __shared__ u16 t[64 * 65];
    const int tid = threadIdx.x;
    const int b = blockIdx.x;
    if (b < 6144) {
        const int zc = b >> 11;
        const int xc = b & 2047;
        const float* src = (zc == 0) ? q : (zc == 1) ? k : v;
        u16* dst = qb + (size_t)zc * 4096 * 1024;
        int off = xc * 2048 + tid * 8;
        float4 v0 = *(const float4*)&src[off];
        float4 v1 = *(const float4*)&src[off + 4];
        uint4 o;
        o.x = (u32)f2bf(v0.x) | ((u32)f2bf(v0.y) << 16);
        o.y = (u32)f2bf(v0.z) | ((u32)f2bf(v0.w) << 16);
        o.z = (u32)f2bf(v1.x) | ((u32)f2bf(v1.y) << 16);
        o.w = (u32)f2bf(v1.z) | ((u32)f2bf(v1.w) << 16);
        *(uint4*)&dst[off] = o;
        return;
    }
    const int tt = b - 6144;
    const int zz = tt >> 8;
    const int bx = tt & 15, by = (tt >> 4) & 15;
    const float* W = (zz == 0) ? W0 : (zz == 1) ? W1 : (zz == 2) ? W2 : W3;
    u16* out = WT + (size_t)zz * 1024 * 1024;
    const int n0 = bx * 64, k0 = by * 64;
#pragma unroll
    for (int it = 0; it < 4; ++it) {
        int flat = it * 256 + tid;
        int r = flat >> 4, c4 = (flat & 15) * 4;
        float4 vv = *(const float4*)&W[(k0 + r) * 1024 + n0 + c4];
        t[r * 65 + c4 + 0] = f2bf(vv.x);
        t[r * 65 + c4 + 1] = f2bf(vv.y);
        t[r * 65 + c4 + 2] = f2bf(vv.z);
        t[r * 65 + c4 + 3] = f2bf(vv.w);
    }
    __syncthreads();
#pragma unroll
    for (int it = 0; it < 2; ++it) {
        int flat = it * 256 + tid;
        int rn = flat >> 3, c8 = (flat & 7) * 8;
        u32 p[4];
#pragma unroll
        for (int e = 0; e < 4; ++e) {
            u32 lo = t[(c8 + 2 * e + 0) * 65 + rn];
            u32 hi = t[(c8 + 2 * e + 1) * 65 + rn];
            p[e] = lo | (hi << 16);
        }
        uint4 o; o.x = p[0]; o.y = p[1]; o.z = p[2]; o.w = p[3];
        *(uint4*)&out[(n0 + rn) * 1024 + k0 + c8] = o;
    }
}

// =====================================================================
// QKV projection GEMM (R1 structure + R10 chunked XCD swizzle):
// 128x128 tile, BK=32, 4 waves (2x2). nf = (flat%8)*96 + flat/8 gives
// each XCD a contiguous 96-block chunk (per-XCD L2 ~3MB, resident).
// =====================================================================
__global__ __launch_bounds__(256) void qkvproj_k(const u16* __restrict__ qb,
                                                 const u16* __restrict__ wt,
                                                 const float* __restrict__ bq,
                                                 const float* __restrict__ bk,
                                                 const float* __restrict__ bv,
                                                 u16* __restrict__ qh,
                                                 u16* __restrict__ kh,
                                                 u16* __restrict__ vhT) {
    __shared__ u16 As[128 * 32];
    __shared__ u16 Bs[128 * 32];
    __shared__ u16 T[128 * 132];
    // chunked XCD swizzle: work id from dispatch id
    const int flat = (blockIdx.z * 32 + blockIdx.y) * 8 + blockIdx.x;
    const int nf   = (flat & 7) * 96 + (flat >> 3);
    const int zz   = nf >> 8;
    const int rem  = nf & 255;
    const int m0   = (rem >> 3) * 128;
    const int n0   = (rem & 7) * 128;

    const u16*   A    = qb + (size_t)zz * 4096 * 1024;
    const u16*   WT   = wt + (size_t)zz * 1024 * 1024;
    const float* bias = (zz == 0) ? bq : (zz == 1) ? bk : bv;
    const bool vmode = (zz == 2);

    const int tid = threadIdx.x;
    const int wid = tid >> 6, lane = tid & 63;
    const int wrow = wid >> 1, wcol = wid & 1;
    const int g = lane >> 4, li = lane & 15;

    f32x4 acc[4][4];
#pragma unroll
    for (int a = 0; a < 4; ++a)
#pragma unroll
        for (int b = 0; b < 4; ++b) acc[a][b] = (f32x4){0.f, 0.f, 0.f, 0.f};

    for (int kt = 0; kt < KTOT / 32; ++kt) {
        const int kb = kt * 32;
#pragma unroll
        for (int cc = 0; cc < 2; ++cc) {
            int c = wid + cc * 4;
            gl_lds16(&A[(m0 + c * 16 + (lane >> 2)) * KTOT + kb + (lane & 3) * 8],
                     &As[c * 512]);
            gl_lds16(&WT[(n0 + c * 16 + (lane >> 2)) * KTOT + kb + (lane & 3) * 8],
                     &Bs[c * 512]);
        }
        __syncthreads();
        bf16x8 af[4], bfr[4];
#pragma unroll
        for (int fr = 0; fr < 4; ++fr)
            af[fr] = *(const bf16x8*)&As[(wrow * 64 + fr * 16 + li) * 32 + g * 8];
#pragma unroll
        for (int fc = 0; fc < 4; ++fc)
            bfr[fc] = *(const bf16x8*)&Bs[(wcol * 64 + fc * 16 + li) * 32 + g * 8];
#pragma unroll
        for (int fr = 0; fr < 4; ++fr)
#pragma unroll
            for (int fc = 0; fc < 4; ++fc)
                acc[fr][fc] = __builtin_amdgcn_mfma_f32_16x16x32_bf16(
                    af[fr], bfr[fc], acc[fr][fc], 0, 0, 0);
        __syncthreads();
    }

#pragma unroll
    for (int fr = 0; fr < 4; ++fr)
#pragma unroll
        for (int fc = 0; fc < 4; ++fc)
#pragma unroll
            for (int reg = 0; reg < 4; ++reg) {
                int rl = wrow * 64 + fr * 16 + g * 4 + reg;
                int cl = wcol * 64 + fc * 16 + li;
                u16 bv16 = f2bf(acc[fr][fc][reg] + bias[n0 + cl]);
                if (!vmode) T[rl * 132 + cl] = bv16;
                else        T[cl * 132 + rl] = bv16;
            }
    __syncthreads();

    const int bb2 = m0 >> 11, ml = m0 & 2047;
    const int lc8 = (tid & 7) * 8;
#pragma unroll
    for (int it = 0; it < 8; ++it) {
        int idx = it * 32 + (tid >> 3);
        int row = idx >> 1, half = idx & 1;
        uint4 val = *(const uint4*)&T[row * 132 + half * 64 + lc8];
        if (!vmode) {
            int h = (n0 >> 6) + half;
            u16* dst = (zz == 0) ? qh : kh;
            *(uint4*)&dst[(((h * 2 + bb2) * 2048 + ml + row) << 6) + lc8] = val;
        } else {
            int cg = n0 + row;
            int h = cg >> 6, d = cg & 63;
            *(uint4*)&vhT[(((h * 2 + bb2) * 64 + d) << 11) + ml + half * 64 + lc8] = val;
        }
    }
}

// =====================================================================
// Out-projection GEMM: y = attnout(bf16) @ WoT^T + bo + res (f32 out).
// R5 geometry (64x128, 512 blocks, 2 blocks/CU) + R10 chunked XCD
// swizzle: nf = (flat%8)*64 + flat/8 (bijective: 512 % 8 == 0).
// =====================================================================
__global__ __launch_bounds__(256) void outproj_k(const u16* __restrict__ A,
                                                 const u16* __restrict__ WT,
                                                 const float* __restrict__ bias,
                                                 const float* __restrict__ res,
                                                 float* __restrict__ outp) {
    __shared__ u16 As[64 * 32];
    __shared__ u16 Bs[128 * 32];
    const int flat = blockIdx.y * 8 + blockIdx.x;
    const int nf   = (flat & 7) * 64 + (flat >> 3);
    const int m0   = (nf >> 3) * 64;
    const int n0   = (nf & 7) * 128;
    const int tid = threadIdx.x;
    const int wid = tid >> 6, lane = tid & 63;
    const int wrow = wid >> 1, wcol = wid & 1;
    const int g = lane >> 4, li = lane & 15;

    f32x4 acc[2][4];
#pragma unroll
    for (int a = 0; a < 2; ++a)
#pragma unroll
        for (int b = 0; b < 4; ++b) acc[a][b] = (f32x4){0.f, 0.f, 0.f, 0.f};

    for (int kt = 0; kt < KTOT / 32; ++kt) {
        const int kb = kt * 32;
        gl_lds16(&A[(m0 + wid * 16 + (lane >> 2)) * KTOT + kb + (lane & 3) * 8],
                 &As[wid * 512]);
#pragma unroll
        for (int cc = 0; cc < 2; ++cc) {
            int c = wid * 2 + cc;
            gl_lds16(&WT[(n0 + c * 16 + (lane >> 2)) * KTOT + kb + (lane & 3) * 8],
                     &Bs[c * 512]);
        }
        __syncthreads();
        bf16x8 af[2], bfr[4];
#pragma unroll
        for (int fr = 0; fr < 2; ++fr)
            af[fr] = *(const bf16x8*)&As[(wrow * 32 + fr * 16 + li) * 32 + g * 8];
#pragma unroll
        for (int fc = 0; fc < 4; ++fc)
            bfr[fc] = *(const bf16x8*)&Bs[(wcol * 64 + fc * 16 + li) * 32 + g * 8];
#pragma unroll
        for (int fr = 0; fr < 2; ++fr)
#pragma unroll
            for (int fc = 0; fc < 4; ++fc)
                acc[fr][fc] = __builtin_amdgcn_mfma_f32_16x16x32_bf16(
                    af[fr], bfr[fc], acc[fr][fc], 0, 0, 0);
        __syncthreads();
    }

#pragma unroll
    for (int fr = 0; fr < 2; ++fr)
#pragma unroll
        for (int fc = 0; fc < 4; ++fc)
#pragma unroll
            for (int reg = 0; reg < 4; ++reg) {
                int r = m0 + wrow * 32 + fr * 16 + g * 4 + reg;
                int c = n0 + wcol * 64 + fc * 16 + li;
                outp[r * NTOT + c] = acc[fr][fc][reg] + bias[c] + res[r * NTOT + c];
            }
}

// =====================================================================
// Attention (R7/R10-proven, 242us): 4-wave/64-row blocks, LDS 40KB,
// grid 1024 => 4 blocks/CU (4 independent barrier groups). Pass A:
// no-max log-sum, 128-row K-tiles, gl_lds dbuf. Pass B: K/V LDS-staged,
// Ps transpose-emit, vmcnt(4) counted barrier wait.
// CHANGE (R11): Ps writes packed b32x2 -> b64 (uint2), 8->4 LDS write
// ops/wave/kt (R8-proven-correct packing, applied without R8's
// occupancy change). Reg-direct operand loads falsified 3x (R2/R3/R9):
// fragment loads scatter 16 cache lines/instr — do not revisit.
// =====================================================================
__global__ __launch_bounds__(256, 4) void attn_k(const u16* __restrict__ qh,
                                                 const u16* __restrict__ kh,
                                                 const u16* __restrict__ vhT,
                                                 float* __restrict__ atn,
                                                 u16* __restrict__ attnout) {
    __shared__ u16 lds[20480];        // 40KB union
    const int tid = threadIdx.x;
    const int D = blockIdx.x;
    const int z = D & 31, q0 = (D >> 5) * 64;
    const int h = z >> 1, bb = z & 1;
    const int wid = tid >> 6, lane = tid & 63, g = lane >> 4, li = lane & 15;
    const int row0 = wid * 16;
    const int zbase = z * SEQ;
    const int swz = li & 7;           // read-side row xor

    // Q fragments (B-operand): lane li -> q-row row0+li, k = ks*32+g*8+e
    bf16x8 aq[2];
#pragma unroll
    for (int ks = 0; ks < 2; ++ks)
        aq[ks] = *(const bf16x8*)
            &qh[(size_t)(zbase + q0 + row0 + li) * 64 + ks * 32 + g * 8];

    // ---------------- pass A: row sums (no max), 128-row K-tiles ---------
    float lmv;
    {
        u16* KsA = lds;                          // [2][8192] u16 (32KB)
        const int ar = lane >> 3;
        const int ac = (lane & 7) ^ ar;          // pre-swizzled source chunk
        const u16* kA[4];
#pragma unroll
        for (int cc = 0; cc < 4; ++cc) {
            int c = wid * 4 + cc;
            kA[cc] = &kh[(size_t)(zbase + c * 8 + ar) * 64 + ac * 8];
            gl_lds16(kA[cc], &KsA[c * 512]);
        }
        __syncthreads();

        float s = 0.f;
        for (int kt = 0; kt < 16; ++kt) {
            const int buf = kt & 1;
            if (kt < 15) {
                const size_t nxt = (size_t)(kt + 1) * 128 * 64;
#pragma unroll
                for (int cc = 0; cc < 4; ++cc)
                    gl_lds16(kA[cc] + nxt,
                             &KsA[(buf ^ 1) * 8192 + (wid * 4 + cc) * 512]);
            }
            f32x4 sv[8];
#pragma unroll
            for (int fc = 0; fc < 8; ++fc) sv[fc] = (f32x4){0.f, 0.f, 0.f, 0.f};
            __builtin_amdgcn_s_setprio(1);
#pragma unroll
            for (int ks = 0; ks < 2; ++ks) {
#pragma unroll
                for (int fc = 0; fc < 8; ++fc) {
                    bf16x8 kf = *(const bf16x8*)
                        &KsA[buf * 8192 + (fc * 16 + li) * 64 + (((ks * 4 + g) ^ swz) * 8)];
                    sv[fc] = __builtin_amdgcn_mfma_f32_16x16x32_bf16(
                        kf, aq[ks], sv[fc], 0, 0, 0);
                }
            }
            __builtin_amdgcn_s_setprio(0);
            float ssum = 0.f;
#pragma unroll
            for (int fc = 0; fc < 8; ++fc)
#pragma unroll
                for (int reg = 0; reg < 4; ++reg)
                    ssum += __builtin_amdgcn_exp2f(sv[fc][reg] * SC2);
            s += ssum;
            __syncthreads();
        }
        s += __shfl_xor(s, 16, 64);
        s += __shfl_xor(s, 32, 64);
        lmv = __builtin_amdgcn_logf(s);          // log2(sum); p = exp2(S'-lmv)
    }

    // ---------------- pass B ----------------
    u16* Ks = lds;                 // [2][4096]
    u16* Vs = lds + 8192;          // [2][4096]
    u16* Ps = lds + 16384;         // [4][1024]
    const int ar8 = lane >> 3;
    const int schunk = (lane & 7) ^ ar8;
    const u16* ksrc[2];
    const u16* vsrc[2];
#pragma unroll
    for (int cc = 0; cc < 2; ++cc) {
        int c = wid * 2 + cc;
        ksrc[cc] = &kh[(size_t)(zbase + c * 8 + ar8) * 64 + schunk * 8];
        vsrc[cc] = &vhT[(size_t)(z * 64 + c * 8 + ar8) * SEQ + schunk * 8];
        gl_lds16(ksrc[cc], &Ks[c * 512]);
        gl_lds16(vsrc[cc], &Vs[c * 512]);
    }
    __syncthreads();

    f32x4 oa[4];
#pragma unroll
    for (int fn = 0; fn < 4; ++fn) oa[fn] = (f32x4){0.f, 0.f, 0.f, 0.f};

    const u16* psw = &Ps[wid * 1024];     // this wave's 16x64 P slice
    const int prow = wid * 1024 + li * 64;
    for (int kt = 0; kt < 32; ++kt) {
        const int buf = kt & 1;
        const int k0 = kt * 64;
        if (kt < 31) {
#pragma unroll
            for (int cc = 0; cc < 2; ++cc) {
                int c = wid * 2 + cc;
                gl_lds16(ksrc[cc] + (size_t)(kt + 1) * 64 * 64,
                         &Ks[(buf ^ 1) * 4096 + c * 512]);
                gl_lds16(vsrc[cc] + (size_t)(kt + 1) * 64,
                         &Vs[(buf ^ 1) * 4096 + c * 512]);
            }
        }

        f32x4 sv[4];
#pragma unroll
        for (int fc = 0; fc < 4; ++fc) sv[fc] = (f32x4){0.f, 0.f, 0.f, 0.f};
        __builtin_amdgcn_s_setprio(1);
#pragma unroll
        for (int ks = 0; ks < 2; ++ks) {
#pragma unroll
            for (int fc = 0; fc < 4; ++fc) {
                bf16x8 kf = *(const bf16x8*)
                    &Ks[buf * 4096 + (fc * 16 + li) * 64 + (((ks * 4 + g) ^ swz) * 8)];
                sv[fc] = __builtin_amdgcn_mfma_f32_16x16x32_bf16(
                    kf, aq[ks], sv[fc], 0, 0, 0);
            }
        }
        __builtin_amdgcn_s_setprio(0);

        // p = exp2(S'-lm) -> bf16 pairs into Ps (b64 packed, swizzled)
#pragma unroll
        for (int fc = 0; fc < 4; ++fc) {
            float p0 = __builtin_amdgcn_exp2f(sv[fc][0] * SC2 - lmv);
            float p1 = __builtin_amdgcn_exp2f(sv[fc][1] * SC2 - lmv);
            float p2 = __builtin_amdgcn_exp2f(sv[fc][2] * SC2 - lmv);
            float p3 = __builtin_amdgcn_exp2f(sv[fc][3] * SC2 - lmv);
            uint2 wv2;
            wv2.x = (u32)f2bf(p0) | ((u32)f2bf(p1) << 16);
            wv2.y = (u32)f2bf(p2) | ((u32)f2bf(p3) << 16);
            int pc = ((fc * 2 + (g >> 1)) ^ swz) * 8 + (g & 1) * 4;
            *(uint2*)&Ps[prow + pc] = wv2;
        }

        // atn emit: transposed readback, 4 rows x 256B contiguous per instr
#pragma unroll
        for (int it2 = 0; it2 < 4; ++it2) {
            int row  = it2 * 4 + (lane >> 4);      // 0..15
            int col8 = lane & 15;                  // 8B unit (4 bf16) in row
            int lc   = col8 >> 1;                  // logical 16B chunk
            uint2 d2 = *(const uint2*)
                &psw[row * 64 + ((lc ^ (row & 7)) << 3) + ((col8 & 1) << 2)];
            f32x4 o4;
            union { u32 u; float f; } c0v, c1v, c2v, c3v;
            c0v.u = (d2.x & 0xffffu) << 16;  c1v.u = d2.x & 0xffff0000u;
            c2v.u = (d2.y & 0xffffu) << 16;  c3v.u = d2.y & 0xffff0000u;
            o4[0] = c0v.f; o4[1] = c1v.f; o4[2] = c2v.f; o4[3] = c3v.f;
            __builtin_nontemporal_store(o4, (f32x4*)
                &atn[(size_t)(zbase + q0 + row0 + row) * SEQ + k0 + col8 * 4]);
        }

        // PV: O^T = V^T * P^T  (A = V-frag, B = P-frag)
        __builtin_amdgcn_s_setprio(1);
#pragma unroll
        for (int ks = 0; ks < 2; ++ks) {
            bf16x8 pf = *(const bf16x8*)&Ps[prow + (((ks * 4 + g) ^ swz) * 8)];
#pragma unroll
            for (int fn = 0; fn < 4; ++fn) {
                bf16x8 vf = *(const bf16x8*)
                    &Vs[buf * 4096 + (fn * 16 + li) * 64 + (((ks * 4 + g) ^ swz) * 8)];
                oa[fn] = __builtin_amdgcn_mfma_f32_16x16x32_bf16(
                    vf, pf, oa[fn], 0, 0, 0);
            }
        }
        __builtin_amdgcn_s_setprio(0);
        // counted wait: queue = [<=4 prior stores][4 gl_lds][4 new stores];
        // vmcnt(4) drains the prefetch loads, lets this tile's stores fly.
        asm volatile("s_waitcnt vmcnt(4) lgkmcnt(0)" ::: "memory");
        __builtin_amdgcn_s_barrier();
    }

    // epilogue: O^T regs -> attnout[bb*2048 + r][h*64 + d], 8B packed stores
#pragma unroll
    for (int fn = 0; fn < 4; ++fn) {
        u32 w0 = (u32)f2bf(oa[fn][0]) | ((u32)f2bf(oa[fn][1]) << 16);
        u32 w1 = (u32)f2bf(oa[fn][2]) | ((u32)f2bf(oa[fn][3]) << 16);
        uint2 wv; wv.x = w0; wv.y = w1;
        *(uint2*)&attnout[(size_t)(bb * SEQ + q0 + row0 + li) * 1024
                          + h * 64 + fn * 16 + g * 4] = wv;
    }
}

// =====================================================================
// Row LayerNorm
// =====================================================================
__global__ __launch_bounds__(256) void ln_k(const float* __restrict__ y,
                                            const float* __restrict__ gamma,
                                            const float* __restrict__ beta,
                                            float* __restrict__ out) {
    __shared__ float red[8];
    const int row = blockIdx.x, tid = threadIdx.x;
    float4 v = *(const float4*)&y[row * 1024 + tid * 4];
    float s = v.x + v.y + v.z + v.w;
    float sq = v.x * v.x + v.y * v.y + v.z * v.z + v.w * v.w;
#pragma unroll
    for (int msk = 1; msk <= 32; msk <<= 1) {
        s += __shfl_xor(s, msk, 64);
        sq += __shfl_xor(sq, msk, 64);
    }
    const int wid = tid >> 6;
    if ((tid & 63) == 0) { red[wid * 2] = s; red[wid * 2 + 1] = sq; }
    __syncthreads();
    s = red[0] + red[2] + red[4] + red[6];
    sq = red[1] + red[3] + red[5] + red[7];
    float mu = s * (1.0f / 1024.0f);
    float var = sq * (1.0f / 1024.0f) - mu * mu;
    float rs = rsqrtf(var + 1e-5f);
    float4 g4 = *(const float4*)&gamma[tid * 4];
    float4 b4 = *(const float4*)&beta[tid * 4];
    float4 o;
    o.x = (v.x - mu) * rs * g4.x + b4.x;
    o.y = (v.y - mu) * rs * g4.y + b4.y;
    o.z = (v.z - mu) * rs * g4.z + b4.z;
    o.w = (v.w - mu) * rs * g4.w + b4.w;
    *(float4*)&out[row * 1024 + tid * 4] = o;
}

// =====================================================================
extern "C" void kernel_launch(void* const* d_in, const int* in_sizes, int n_in,
                              void* d_out, int out_size, void* d_ws, size_t ws_size,
                              hipStream_t stream) {
    const float* q     = (const float*)d_in[0];
    const float* k     = (const float*)d_in[1];
    const float* v     = (const float*)d_in[2];
    const float* Wq    = (const float*)d_in[3];
    const float* bq    = (const float*)d_in[4];
    const float* Wk    = (const float*)d_in[5];
    const float* bk    = (const float*)d_in[6];
    const float* Wv    = (const float*)d_in[7];
    const float* bv    = (const float*)d_in[8];
    const float* Wo    = (const float*)d_in[9];
    const float* bo    = (const float*)d_in[10];
    const float* gamma = (const float*)d_in[11];
    const float* beta  = (const float*)d_in[12];

    float* out = (float*)d_out;               // [2,2048,1024] f32
    float* atn = out + 4096 * 1024;           // [32,2048,2048] f32

    // ws (56 MB): wt 8MB | qb 24MB {aliased: attnout 8MB, y 16MB} |
    //             qh 8 | kh 8 | vhT 8
    u16* wt  = (u16*)d_ws;                    // 4x [1024][1024] bf16
    u16* qb  = wt + 4 * 1024 * 1024;          // 3x [4096][1024] bf16
    u16* attnout = qb;                        // alias: qb dead after qkvproj
    float* y = (float*)(qb + 4096 * 1024);    // alias: after attnout region
    u16* qh  = qb + 3 * 4096 * 1024;
    u16* kh  = qh + NZ * SEQ * 64;
    u16* vhT = kh + NZ * SEQ * 64;
    u16* wto = wt + 3 * 1024 * 1024;

    dim3 tb(256);
    prep_k<<<dim3(7168), tb, 0, stream>>>(q, k, v, Wq, Wk, Wv, Wo, qb, wt);

    qkvproj_k<<<dim3(8, 32, 3), tb, 0, stream>>>(qb, wt, bq, bk, bv,
                                                 qh, kh, vhT);

    attn_k<<<dim3(1024), tb, 0, stream>>>(qh, kh, vhT, atn, attnout);

    outproj_k<<<dim3(8, 64), tb, 0, stream>>>(attnout, wto, bo, q, y);

    ln_k<<<dim3(4096), tb, 0, stream>>>(y, gamma, beta, out);
}